// Round 1
// baseline (596.290 us; speedup 1.0000x reference)
//
#include <hip/hip_runtime.h>

typedef __attribute__((ext_vector_type(8))) short bf8;
typedef __attribute__((ext_vector_type(4))) float f4;

constexpr int B_ = 8, CIN = 256, CINT = 128, NN = 4096;

__device__ __forceinline__ unsigned short f2bf(float f) {
  unsigned int u = __builtin_bit_cast(unsigned int, f);
  u += 0x7FFFu + ((u >> 16) & 1u);   // round-to-nearest-even
  return (unsigned short)(u >> 16);
}

// ---------------- Projection: theta/phi [b][n][128] bf16, gT [b][128][n] bf16
__global__ __launch_bounds__(256) void proj_kernel(
    const float* __restrict__ x,
    const float* __restrict__ wth, const float* __restrict__ bth,
    const float* __restrict__ wph, const float* __restrict__ bph,
    const float* __restrict__ wg,  const float* __restrict__ bg,
    unsigned short* __restrict__ theta,
    unsigned short* __restrict__ phi,
    unsigned short* __restrict__ gT)
{
  const int b  = blockIdx.y;
  const int n0 = blockIdx.x * 64;
  const int w  = threadIdx.x >> 6;
  const int l  = threadIdx.x & 63;
  const int lr = l & 15, lg = l >> 4;
  const float* xb = x + (size_t)b * CIN * NN;

  for (int mt = 0; mt < 4; ++mt) {
    const int m0 = n0 + mt * 16;
    // B-operand fragments from x (K-major): b[j] = X[k][m], k = ks*32+lg*8+j
    bf8 bx[8];
    #pragma unroll
    for (int ks = 0; ks < 8; ++ks) {
      #pragma unroll
      for (int j = 0; j < 8; ++j)
        bx[ks][j] = (short)f2bf(xb[(size_t)(ks * 32 + lg * 8 + j) * NN + m0 + lr]);
    }
    #pragma unroll
    for (int dti = 0; dti < 6; ++dti) {
      const int dt  = w * 6 + dti;          // 24 d-tiles over 3 matrices
      const int mat = dt >> 3;
      const int d0  = (dt & 7) * 16;
      const float* W  = (mat == 0) ? wth : (mat == 1) ? wph : wg;
      const float* Bv = (mat == 0) ? bth : (mat == 1) ? bph : bg;
      f4 acc = {0.f, 0.f, 0.f, 0.f};
      #pragma unroll
      for (int ks = 0; ks < 8; ++ks) {
        const float* wr = W + (size_t)(d0 + lr) * CIN + ks * 32 + lg * 8;
        float4 w0 = *(const float4*)wr;
        float4 w1 = *(const float4*)(wr + 4);
        bf8 aw;
        aw[0] = (short)f2bf(w0.x); aw[1] = (short)f2bf(w0.y);
        aw[2] = (short)f2bf(w0.z); aw[3] = (short)f2bf(w0.w);
        aw[4] = (short)f2bf(w1.x); aw[5] = (short)f2bf(w1.y);
        aw[6] = (short)f2bf(w1.z); aw[7] = (short)f2bf(w1.w);
        acc = __builtin_amdgcn_mfma_f32_16x16x32_bf16(aw, bx[ks], acc, 0, 0, 0);
      }
      // D layout: row (=d offset) = lg*4+r, col (=m offset) = lr
      const int m = m0 + lr;
      if (mat < 2) {
        unsigned short* dst =
            ((mat == 0) ? theta : phi) + ((size_t)b * NN + m) * CINT + d0 + lg * 4;
        ushort4 h;
        h.x = f2bf(acc[0] + Bv[d0 + lg * 4 + 0]);
        h.y = f2bf(acc[1] + Bv[d0 + lg * 4 + 1]);
        h.z = f2bf(acc[2] + Bv[d0 + lg * 4 + 2]);
        h.w = f2bf(acc[3] + Bv[d0 + lg * 4 + 3]);
        *(ushort4*)dst = h;
      } else {
        #pragma unroll
        for (int r = 0; r < 4; ++r) {
          const int d = d0 + lg * 4 + r;
          gT[((size_t)b * CINT + d) * NN + m] = f2bf(acc[r] + Bv[d]);
        }
      }
    }
  }
}

// ---------------- Attention: per wave 16 q-rows, loop k in tiles of 64
__global__ __launch_bounds__(256) void attn_kernel(
    const unsigned short* __restrict__ theta,
    const unsigned short* __restrict__ phi,
    const unsigned short* __restrict__ gT,
    float* __restrict__ out)
{
  const int b  = blockIdx.y;
  const int w  = threadIdx.x >> 6;
  const int q0 = blockIdx.x * 64 + w * 16;
  const int l  = threadIdx.x & 63;
  const int lr = l & 15, lg = l >> 4;

  __shared__ unsigned short Pl[4][16][72];   // per-wave P tile, 144B rows (16B aligned)
  unsigned short (*P)[72] = Pl[w];

  const unsigned short* th = theta + ((size_t)b * NN + q0) * CINT;
  const unsigned short* ph = phi + (size_t)b * NN * CINT;
  const unsigned short* gt = gT + (size_t)b * CINT * NN;

  // Q fragments, resident in regs: a[j] = theta[q0+lr][ds*32 + lg*8 + j]
  bf8 qf[4];
  #pragma unroll
  for (int ds = 0; ds < 4; ++ds)
    qf[ds] = *(const bf8*)(th + (size_t)lr * CINT + ds * 32 + lg * 8);

  f4 y[8];
  #pragma unroll
  for (int dt = 0; dt < 8; ++dt) y[dt] = (f4){0.f, 0.f, 0.f, 0.f};
  float rs[4] = {0.f, 0.f, 0.f, 0.f};

  for (int k0 = 0; k0 < NN; k0 += 64) {
    // ---- QK^T : 4 S-tiles of 16x16
    f4 s[4];
    #pragma unroll
    for (int st = 0; st < 4; ++st) {
      s[st] = (f4){0.f, 0.f, 0.f, 0.f};
      const unsigned short* pr = ph + (size_t)(k0 + st * 16 + lr) * CINT + lg * 8;
      #pragma unroll
      for (int ds = 0; ds < 4; ++ds)
        s[st] = __builtin_amdgcn_mfma_f32_16x16x32_bf16(
            qf[ds], *(const bf8*)(pr + ds * 32), s[st], 0, 0, 0);
    }
    // ---- unnormalized softmax: p = exp(S); per-lane rowsum partials
    #pragma unroll
    for (int st = 0; st < 4; ++st) {
      #pragma unroll
      for (int r = 0; r < 4; ++r) {
        float p = __expf(s[st][r]);
        rs[r] += p;
        P[lg * 4 + r][st * 16 + lr] = f2bf(p);   // P[q-off][k-off]
      }
    }
    // ---- PV: A = P rows (LDS), B = gT rows (contiguous along n)
    bf8 pa0 = *(const bf8*)&P[lr][lg * 8];
    bf8 pa1 = *(const bf8*)&P[lr][32 + lg * 8];
    #pragma unroll
    for (int dt = 0; dt < 8; ++dt) {
      const unsigned short* g0 = gt + (size_t)(dt * 16 + lr) * NN + k0 + lg * 8;
      y[dt] = __builtin_amdgcn_mfma_f32_16x16x32_bf16(
          pa0, *(const bf8*)g0, y[dt], 0, 0, 0);
      y[dt] = __builtin_amdgcn_mfma_f32_16x16x32_bf16(
          pa1, *(const bf8*)(g0 + 32), y[dt], 0, 0, 0);
    }
  }

  // final cross-lane rowsum (lanes sharing lg hold the same rows)
  #pragma unroll
  for (int r = 0; r < 4; ++r) {
    float v = rs[r];
    v += __shfl_xor(v, 1);
    v += __shfl_xor(v, 2);
    v += __shfl_xor(v, 4);
    v += __shfl_xor(v, 8);
    rs[r] = 1.0f / v;
  }
  float* ob = out + (size_t)b * CINT * NN;
  #pragma unroll
  for (int dt = 0; dt < 8; ++dt) {
    #pragma unroll
    for (int r = 0; r < 4; ++r)
      ob[(size_t)(dt * 16 + lr) * NN + q0 + lg * 4 + r] = y[dt][r] * rs[r];
  }
}

extern "C" void kernel_launch(void* const* d_in, const int* in_sizes, int n_in,
                              void* d_out, int out_size, void* d_ws, size_t ws_size,
                              hipStream_t stream) {
  const float* x   = (const float*)d_in[0];
  const float* wth = (const float*)d_in[1];
  const float* bth = (const float*)d_in[2];
  const float* wph = (const float*)d_in[3];
  const float* bph = (const float*)d_in[4];
  const float* wg  = (const float*)d_in[5];
  const float* bg  = (const float*)d_in[6];
  float* out = (float*)d_out;

  unsigned short* theta = (unsigned short*)d_ws;
  unsigned short* phi   = theta + (size_t)B_ * NN * CINT;
  unsigned short* gT    = phi   + (size_t)B_ * NN * CINT;

  dim3 grid(64, 8), blk(256);
  hipLaunchKernelGGL(proj_kernel, grid, blk, 0, stream,
                     x, wth, bth, wph, bph, wg, bg, theta, phi, gT);
  hipLaunchKernelGGL(attn_kernel, grid, blk, 0, stream, theta, phi, gT, out);
}

// Round 2
// 311.834 us; speedup vs baseline: 1.9122x; 1.9122x over previous
//
#include <hip/hip_runtime.h>

typedef __attribute__((ext_vector_type(8))) short bf8;
typedef __attribute__((ext_vector_type(4))) float f4;
typedef unsigned short u16;

constexpr int B_ = 8, CIN = 256, CINT = 128, NN = 4096;

__device__ __forceinline__ u16 f2bf(float f) {
  unsigned int u = __builtin_bit_cast(unsigned int, f);
  u += 0x7FFFu + ((u >> 16) & 1u);   // round-to-nearest-even
  return (u16)(u >> 16);
}

// ---------------- Projection: theta/phi [b][n][128] bf16, gT [b][128][n] bf16
__global__ __launch_bounds__(256) void proj_kernel(
    const float* __restrict__ x,
    const float* __restrict__ wth, const float* __restrict__ bth,
    const float* __restrict__ wph, const float* __restrict__ bph,
    const float* __restrict__ wg,  const float* __restrict__ bg,
    u16* __restrict__ theta, u16* __restrict__ phi, u16* __restrict__ gT)
{
  const int b  = blockIdx.y;
  const int n0 = blockIdx.x * 64;
  const int w  = threadIdx.x >> 6;
  const int l  = threadIdx.x & 63;
  const int lr = l & 15, lg = l >> 4;
  const float* xb = x + (size_t)b * CIN * NN;

  for (int mt = 0; mt < 4; ++mt) {
    const int m0 = n0 + mt * 16;
    bf8 bx[8];
    #pragma unroll
    for (int ks = 0; ks < 8; ++ks) {
      #pragma unroll
      for (int j = 0; j < 8; ++j)
        bx[ks][j] = (short)f2bf(xb[(size_t)(ks * 32 + lg * 8 + j) * NN + m0 + lr]);
    }
    #pragma unroll
    for (int dti = 0; dti < 6; ++dti) {
      const int dt  = w * 6 + dti;
      const int mat = dt >> 3;
      const int d0  = (dt & 7) * 16;
      const float* W  = (mat == 0) ? wth : (mat == 1) ? wph : wg;
      const float* Bv = (mat == 0) ? bth : (mat == 1) ? bph : bg;
      f4 acc = {0.f, 0.f, 0.f, 0.f};
      #pragma unroll
      for (int ks = 0; ks < 8; ++ks) {
        const float* wr = W + (size_t)(d0 + lr) * CIN + ks * 32 + lg * 8;
        float4 w0 = *(const float4*)wr;
        float4 w1 = *(const float4*)(wr + 4);
        bf8 aw;
        aw[0] = (short)f2bf(w0.x); aw[1] = (short)f2bf(w0.y);
        aw[2] = (short)f2bf(w0.z); aw[3] = (short)f2bf(w0.w);
        aw[4] = (short)f2bf(w1.x); aw[5] = (short)f2bf(w1.y);
        aw[6] = (short)f2bf(w1.z); aw[7] = (short)f2bf(w1.w);
        acc = __builtin_amdgcn_mfma_f32_16x16x32_bf16(aw, bx[ks], acc, 0, 0, 0);
      }
      const int m = m0 + lr;
      if (mat < 2) {
        u16* dst = ((mat == 0) ? theta : phi) + ((size_t)b * NN + m) * CINT + d0 + lg * 4;
        ushort4 h;
        h.x = f2bf(acc[0] + Bv[d0 + lg * 4 + 0]);
        h.y = f2bf(acc[1] + Bv[d0 + lg * 4 + 1]);
        h.z = f2bf(acc[2] + Bv[d0 + lg * 4 + 2]);
        h.w = f2bf(acc[3] + Bv[d0 + lg * 4 + 3]);
        *(ushort4*)dst = h;
      } else {
        #pragma unroll
        for (int r = 0; r < 4; ++r) {
          const int d = d0 + lg * 4 + r;
          gT[((size_t)b * CINT + d) * NN + m] = f2bf(acc[r] + Bv[d]);
        }
      }
    }
  }
}

// ---------------- Attention: 4 waves x 32 q-rows, k-tiles of 64, dbuf LDS
__global__ __launch_bounds__(256, 1) void attn_kernel(
    const u16* __restrict__ theta, const u16* __restrict__ phi,
    const u16* __restrict__ gT, float* __restrict__ out)
{
  const int b  = blockIdx.y;
  const int t_ = threadIdx.x;
  const int w  = t_ >> 6;
  const int l  = t_ & 63;
  const int lr = l & 15, lg = l >> 4;
  const int qw = blockIdx.x * 128 + w * 32;

  // XOR-swizzled tiles: 16B chunk index ^= (row&7)  -> all reads 2 lanes/bank
  __shared__ __align__(16) u16 sphi[2][64 * 128];  // [k-row][d], 16 chunks/row
  __shared__ __align__(16) u16 sg[2][128 * 64];    // [d-row][k],  8 chunks/row
  __shared__ __align__(16) u16 sP[4][32 * 64];     // per-wave P,  8 chunks/row

  const u16* th = theta + (size_t)b * NN * CINT;
  const u16* ph = phi + (size_t)b * NN * CINT;
  const u16* gt = gT + (size_t)b * CINT * NN;

  // Q fragments resident in regs: A[m=lr within tile][k=lg*8+j]
  bf8 qf[2][4];
  #pragma unroll
  for (int qt = 0; qt < 2; ++qt)
    #pragma unroll
    for (int ds = 0; ds < 4; ++ds)
      qf[qt][ds] = *(const bf8*)(th + (size_t)(qw + qt * 16 + lr) * CINT + ds * 32 + lg * 8);

  f4 y[2][8];
  #pragma unroll
  for (int qt = 0; qt < 2; ++qt)
    #pragma unroll
    for (int dt = 0; dt < 8; ++dt) y[qt][dt] = (f4){0.f, 0.f, 0.f, 0.f};
  float rs[2][4] = {{0.f,0.f,0.f,0.f},{0.f,0.f,0.f,0.f}};

  uint4 rp[4], rg[4];   // staged regs (T14 split: load early, write late)

  #define STAGE_LOAD(K0)                                                        \
    {                                                                           \
      _Pragma("unroll")                                                         \
      for (int c = 0; c < 4; ++c) {                                             \
        int i = c * 256 + t_;                                                   \
        rp[c] = *(const uint4*)(ph + (size_t)((K0) + (i >> 4)) * CINT + (i & 15) * 8); \
        rg[c] = *(const uint4*)(gt + (size_t)(i >> 3) * NN + (K0) + (i & 7) * 8);      \
      }                                                                         \
    }
  #define STAGE_WRITE(BUF)                                                      \
    {                                                                           \
      _Pragma("unroll")                                                         \
      for (int c = 0; c < 4; ++c) {                                             \
        int i = c * 256 + t_;                                                   \
        int r1 = i >> 4, c1 = i & 15;                                           \
        *(uint4*)&sphi[BUF][r1 * 128 + (c1 ^ (r1 & 7)) * 8] = rp[c];            \
        int r2 = i >> 3, c2 = i & 7;                                            \
        *(uint4*)&sg[BUF][r2 * 64 + (c2 ^ (r2 & 7)) * 8] = rg[c];               \
      }                                                                         \
    }

  // prologue: stage tile 0
  STAGE_LOAD(0);
  STAGE_WRITE(0);
  __syncthreads();
  int cur = 0;

  for (int t = 0; t < 64; ++t) {
    const int k0 = t * 64;
    if (t < 63) STAGE_LOAD(k0 + 64);

    // ---- QK^T: S[2 qtiles][4 ktiles], B-frag from swizzled sphi
    f4 s[2][4];
    #pragma unroll
    for (int qt = 0; qt < 2; ++qt)
      #pragma unroll
      for (int st = 0; st < 4; ++st) s[qt][st] = (f4){0.f, 0.f, 0.f, 0.f};
    #pragma unroll
    for (int st = 0; st < 4; ++st) {
      const int row = st * 16 + lr;
      #pragma unroll
      for (int ds = 0; ds < 4; ++ds) {
        bf8 bf = *(const bf8*)&sphi[cur][row * 128 + (((ds << 2) + lg) ^ (lr & 7)) * 8];
        #pragma unroll
        for (int qt = 0; qt < 2; ++qt)
          s[qt][st] = __builtin_amdgcn_mfma_f32_16x16x32_bf16(qf[qt][ds], bf, s[qt][st], 0, 0, 0);
      }
    }

    // ---- unnormalized exp + P write (swizzled), per-lane rowsum partials
    #pragma unroll
    for (int qt = 0; qt < 2; ++qt)
      #pragma unroll
      for (int st = 0; st < 4; ++st)
        #pragma unroll
        for (int r = 0; r < 4; ++r) {
          float p = __expf(s[qt][st][r]);
          rs[qt][r] += p;
          const int q = qt * 16 + lg * 4 + r;
          const int k = st * 16 + lr;
          sP[w][q * 64 + (((k >> 3) ^ (q & 7)) << 3) + (k & 7)] = f2bf(p);
        }

    // ---- P A-fragments (same-wave LDS, in-order: no barrier needed)
    bf8 paf[2][2];
    #pragma unroll
    for (int qt = 0; qt < 2; ++qt)
      #pragma unroll
      for (int ks = 0; ks < 2; ++ks) {
        const int q = qt * 16 + lr;
        paf[qt][ks] = *(const bf8*)&sP[w][q * 64 + (((ks << 2) + lg) ^ (lr & 7)) * 8];
      }

    // ---- PV: y += P * gT, B-frag from swizzled sg
    #pragma unroll
    for (int dt = 0; dt < 8; ++dt) {
      const int row = dt * 16 + lr;
      #pragma unroll
      for (int ks = 0; ks < 2; ++ks) {
        bf8 gf = *(const bf8*)&sg[cur][row * 64 + (((ks << 2) + lg) ^ (lr & 7)) * 8];
        #pragma unroll
        for (int qt = 0; qt < 2; ++qt)
          y[qt][dt] = __builtin_amdgcn_mfma_f32_16x16x32_bf16(paf[qt][ks], gf, y[qt][dt], 0, 0, 0);
      }
    }

    if (t < 63) STAGE_WRITE(cur ^ 1);
    __syncthreads();
    cur ^= 1;
  }

  // final cross-lane rowsum over lr (lane bits 0..3)
  f4 rsi[2];
  #pragma unroll
  for (int qt = 0; qt < 2; ++qt)
    #pragma unroll
    for (int r = 0; r < 4; ++r) {
      float v = rs[qt][r];
      v += __shfl_xor(v, 1);
      v += __shfl_xor(v, 2);
      v += __shfl_xor(v, 4);
      v += __shfl_xor(v, 8);
      rsi[qt][r] = 1.0f / v;
    }
  float* ob = out + (size_t)b * CINT * NN;
  #pragma unroll
  for (int dt = 0; dt < 8; ++dt)
    #pragma unroll
    for (int qt = 0; qt < 2; ++qt) {
      f4 v = y[qt][dt] * rsi[qt];
      *(float4*)&ob[(size_t)(dt * 16 + lr) * NN + qw + qt * 16 + lg * 4] =
          *(float4*)&v;
    }
}

extern "C" void kernel_launch(void* const* d_in, const int* in_sizes, int n_in,
                              void* d_out, int out_size, void* d_ws, size_t ws_size,
                              hipStream_t stream) {
  const float* x   = (const float*)d_in[0];
  const float* wth = (const float*)d_in[1];
  const float* bth = (const float*)d_in[2];
  const float* wph = (const float*)d_in[3];
  const float* bph = (const float*)d_in[4];
  const float* wg  = (const float*)d_in[5];
  const float* bg  = (const float*)d_in[6];
  float* out = (float*)d_out;

  u16* theta = (u16*)d_ws;
  u16* phi   = theta + (size_t)B_ * NN * CINT;
  u16* gT    = phi   + (size_t)B_ * NN * CINT;

  dim3 gproj(64, 8), blk(256);
  hipLaunchKernelGGL(proj_kernel, gproj, blk, 0, stream,
                     x, wth, bth, wph, bph, wg, bg, theta, phi, gT);
  dim3 gattn(32, 8);
  hipLaunchKernelGGL(attn_kernel, gattn, blk, 0, stream, theta, phi, gT, out);
}

// Round 3
// 144.124 us; speedup vs baseline: 4.1373x; 2.1637x over previous
//
#include <hip/hip_runtime.h>

typedef __attribute__((ext_vector_type(8))) short bf8;
typedef __attribute__((ext_vector_type(4))) float f4;
typedef unsigned short u16;

constexpr int B_ = 8, CIN = 256, CINT = 128, NN = 4096;

__device__ __forceinline__ u16 f2bf(float f) {
  unsigned int u = __builtin_bit_cast(unsigned int, f);
  u += 0x7FFFu + ((u >> 16) & 1u);   // round-to-nearest-even
  return (u16)(u >> 16);
}

// ---------------- Projection.
// theta: [b][n][128] row-major bf16 (attn reads it into regs directly).
// phiT:  tiled [b][kt=n/64][r=n%64][128d], 16B-chunk XOR-swizzled (c16 ^= r&7),
//        values pre-scaled by log2(e) so attn softmax is a raw exp2.
// gTt:   tiled [b][kt][d=0..127][64k], 16B-chunk XOR-swizzled (c16 ^= d&7).
__global__ __launch_bounds__(256) void proj_kernel(
    const float* __restrict__ x,
    const float* __restrict__ wth, const float* __restrict__ bth,
    const float* __restrict__ wph, const float* __restrict__ bph,
    const float* __restrict__ wg,  const float* __restrict__ bg,
    u16* __restrict__ theta, u16* __restrict__ phiT, u16* __restrict__ gTt)
{
  const int b  = blockIdx.y;
  const int n0 = blockIdx.x * 64;
  const int w  = threadIdx.x >> 6;
  const int l  = threadIdx.x & 63;
  const int lr = l & 15, lg = l >> 4;
  const float* xb = x + (size_t)b * CIN * NN;

  for (int mt = 0; mt < 4; ++mt) {
    const int m0 = n0 + mt * 16;
    bf8 bx[8];
    #pragma unroll
    for (int ks = 0; ks < 8; ++ks) {
      #pragma unroll
      for (int j = 0; j < 8; ++j)
        bx[ks][j] = (short)f2bf(xb[(size_t)(ks * 32 + lg * 8 + j) * NN + m0 + lr]);
    }
    #pragma unroll
    for (int dti = 0; dti < 6; ++dti) {
      const int dt  = w * 6 + dti;
      const int mat = dt >> 3;
      const int d0  = (dt & 7) * 16;
      const float* W  = (mat == 0) ? wth : (mat == 1) ? wph : wg;
      const float* Bv = (mat == 0) ? bth : (mat == 1) ? bph : bg;
      f4 acc = {0.f, 0.f, 0.f, 0.f};
      #pragma unroll
      for (int ks = 0; ks < 8; ++ks) {
        const float* wr = W + (size_t)(d0 + lr) * CIN + ks * 32 + lg * 8;
        float4 w0 = *(const float4*)wr;
        float4 w1 = *(const float4*)(wr + 4);
        bf8 aw;
        aw[0] = (short)f2bf(w0.x); aw[1] = (short)f2bf(w0.y);
        aw[2] = (short)f2bf(w0.z); aw[3] = (short)f2bf(w0.w);
        aw[4] = (short)f2bf(w1.x); aw[5] = (short)f2bf(w1.y);
        aw[6] = (short)f2bf(w1.z); aw[7] = (short)f2bf(w1.w);
        acc = __builtin_amdgcn_mfma_f32_16x16x32_bf16(aw, bx[ks], acc, 0, 0, 0);
      }
      const int m  = m0 + lr;          // n index
      const int kt = m >> 6, rr = m & 63;
      const int dlo = d0 + lg * 4;
      if (mat == 0) {
        u16* dst = theta + ((size_t)b * NN + m) * CINT + dlo;
        ushort4 h4;
        h4.x = f2bf(acc[0] + Bv[dlo + 0]);
        h4.y = f2bf(acc[1] + Bv[dlo + 1]);
        h4.z = f2bf(acc[2] + Bv[dlo + 2]);
        h4.w = f2bf(acc[3] + Bv[dlo + 3]);
        *(ushort4*)dst = h4;
      } else if (mat == 1) {
        const int c16 = dlo >> 3;
        const int swz = c16 ^ (rr & 7);
        u16* dst = phiT + ((size_t)(b * 64 + kt)) * 8192 + rr * 128 + swz * 8 + (lg & 1) * 4;
        constexpr float L2E = 1.44269504088896f;
        ushort4 h4;
        h4.x = f2bf((acc[0] + Bv[dlo + 0]) * L2E);
        h4.y = f2bf((acc[1] + Bv[dlo + 1]) * L2E);
        h4.z = f2bf((acc[2] + Bv[dlo + 2]) * L2E);
        h4.w = f2bf((acc[3] + Bv[dlo + 3]) * L2E);
        *(ushort4*)dst = h4;
      } else {
        #pragma unroll
        for (int r = 0; r < 4; ++r) {
          const int d = dlo + r;
          gTt[(size_t)(b * 64 + kt) * 8192 + d * 64 + (((rr >> 3) ^ (d & 7)) * 8) + (rr & 7)]
              = f2bf(acc[r] + Bv[d]);
        }
      }
    }
  }
}

// ---------------- Attention: 8 waves; waves 0-3 = k-half 0, waves 4-7 = k-half 1.
// Each wave: 32 q-rows, swapped QK^T (mfma(phi, theta)) so P is k-contiguous per lane.
__global__ __launch_bounds__(512, 2) void attn_kernel(
    const u16* __restrict__ theta, const u16* __restrict__ phiT,
    const u16* __restrict__ gTt, float* __restrict__ out)
{
  const int b  = blockIdx.y;
  const int t_ = threadIdx.x;
  const int w  = t_ >> 6;
  const int l  = t_ & 63;
  const int lr = l & 15, lg = l >> 4;
  const int h  = w >> 2, wq = w & 3;
  const int qw = blockIdx.x * 128 + wq * 32;

  __shared__ __align__(16) u16 sphi[2][2][64 * 128];  // [half][buf] 16KB tiles
  __shared__ __align__(16) u16 sg[2][2][128 * 64];
  __shared__ __align__(16) u16 sP[8][16 * 64];        // per-wave, reused per qt

  const u16* th = theta + (size_t)b * NN * CINT;

  // theta fragments (B-operand of swapped QK^T), resident in regs
  bf8 qf[2][4];
  #pragma unroll
  for (int qt = 0; qt < 2; ++qt)
    #pragma unroll
    for (int ds = 0; ds < 4; ++ds)
      qf[qt][ds] = *(const bf8*)(th + (size_t)(qw + qt * 16 + lr) * CINT + ds * 32 + lg * 8);

  f4 y[2][8];
  #pragma unroll
  for (int qt = 0; qt < 2; ++qt)
    #pragma unroll
    for (int dt = 0; dt < 8; ++dt) y[qt][dt] = (f4){0.f, 0.f, 0.f, 0.f};
  float rs[2] = {0.f, 0.f};

  const int th256 = t_ & 255;   // thread id within the half
  const u16* psrc = phiT + (size_t)(b * 64 + h * 32) * 8192;
  const u16* gsrc = gTt  + (size_t)(b * 64 + h * 32) * 8192;

  uint4 rp[4], rg[4];
  #define SLOAD(T)                                                              \
    { _Pragma("unroll")                                                         \
      for (int c = 0; c < 4; ++c) {                                             \
        rp[c] = *(const uint4*)(psrc + (size_t)(T) * 8192 + c * 2048 + th256 * 8); \
        rg[c] = *(const uint4*)(gsrc + (size_t)(T) * 8192 + c * 2048 + th256 * 8); \
      } }
  #define SWRITE(BUF)                                                           \
    { _Pragma("unroll")                                                         \
      for (int c = 0; c < 4; ++c) {                                             \
        *(uint4*)&sphi[h][BUF][c * 2048 + th256 * 8] = rp[c];                   \
        *(uint4*)&sg[h][BUF][c * 2048 + th256 * 8]   = rg[c];                   \
      } }

  SLOAD(0); SWRITE(0);
  __syncthreads();
  int cur = 0;

  for (int t = 0; t < 32; ++t) {
    if (t < 31) SLOAD(t + 1);

    // ---- swapped QK^T: S^T tiles; A = phi rows (k), B = theta rows (q)
    f4 s[2][4];
    #pragma unroll
    for (int qt = 0; qt < 2; ++qt)
      #pragma unroll
      for (int st = 0; st < 4; ++st) s[qt][st] = (f4){0.f, 0.f, 0.f, 0.f};
    __builtin_amdgcn_s_setprio(1);
    #pragma unroll
    for (int st = 0; st < 4; ++st) {
      const u16* base = &sphi[h][cur][(st * 16 + lr) * 128];
      #pragma unroll
      for (int ds = 0; ds < 4; ++ds) {
        bf8 af = *(const bf8*)(base + (((ds * 4 + lg) ^ (lr & 7)) * 8));
        #pragma unroll
        for (int qt = 0; qt < 2; ++qt)
          s[qt][st] = __builtin_amdgcn_mfma_f32_16x16x32_bf16(af, qf[qt][ds], s[qt][st], 0, 0, 0);
      }
    }
    __builtin_amdgcn_s_setprio(0);

    // ---- preload g fragments (shared across both qt passes)
    bf8 gfr[8][2];
    #pragma unroll
    for (int dt = 0; dt < 8; ++dt)
      #pragma unroll
      for (int ks = 0; ks < 2; ++ks)
        gfr[dt][ks] = *(const bf8*)&sg[h][cur][(dt * 16 + lr) * 64 + (((ks * 4 + lg) ^ (lr & 7)) * 8)];

    // ---- per-qt: exp2, pack b64 into sP, read P-fragments, PV MFMAs
    #pragma unroll
    for (int qt = 0; qt < 2; ++qt) {
      #pragma unroll
      for (int st = 0; st < 4; ++st) {
        float p0 = __builtin_amdgcn_exp2f(s[qt][st][0]);
        float p1 = __builtin_amdgcn_exp2f(s[qt][st][1]);
        float p2 = __builtin_amdgcn_exp2f(s[qt][st][2]);
        float p3 = __builtin_amdgcn_exp2f(s[qt][st][3]);
        rs[qt] += (p0 + p1) + (p2 + p3);
        ushort4 pk;
        pk.x = f2bf(p0); pk.y = f2bf(p1); pk.z = f2bf(p2); pk.w = f2bf(p3);
        *(ushort4*)&sP[w][lr * 64 + (((st * 2 + (lg >> 1)) ^ (lr & 7)) << 3) + ((lg & 1) << 2)] = pk;
      }
      bf8 paf[2];
      #pragma unroll
      for (int ks = 0; ks < 2; ++ks)
        paf[ks] = *(const bf8*)&sP[w][lr * 64 + ((((ks << 2) + lg) ^ (lr & 7)) << 3)];
      __builtin_amdgcn_s_setprio(1);
      #pragma unroll
      for (int dt = 0; dt < 8; ++dt) {
        y[qt][dt] = __builtin_amdgcn_mfma_f32_16x16x32_bf16(paf[0], gfr[dt][0], y[qt][dt], 0, 0, 0);
        y[qt][dt] = __builtin_amdgcn_mfma_f32_16x16x32_bf16(paf[1], gfr[dt][1], y[qt][dt], 0, 0, 0);
      }
      __builtin_amdgcn_s_setprio(0);
    }

    if (t < 31) SWRITE(cur ^ 1);
    __syncthreads();
    cur ^= 1;
  }

  // ---- combine the two k-halves through LDS (reuse sphi/sg space)
  float* ycomb  = (float*)&sphi[0][0][0];   // 64KB: 4 waves x 16KB
  float* rscomb = (float*)&sg[0][0][0];
  if (h == 1) {
    #pragma unroll
    for (int qt = 0; qt < 2; ++qt) {
      #pragma unroll
      for (int dt = 0; dt < 8; ++dt)
        *(f4*)&ycomb[wq * 4096 + (qt * 8 + dt) * 256 + l * 4] = y[qt][dt];
      rscomb[wq * 128 + qt * 64 + l] = rs[qt];
    }
  }
  __syncthreads();
  if (h == 0) {
    #pragma unroll
    for (int qt = 0; qt < 2; ++qt) {
      #pragma unroll
      for (int dt = 0; dt < 8; ++dt)
        y[qt][dt] += *(const f4*)&ycomb[wq * 4096 + (qt * 8 + dt) * 256 + l * 4];
      rs[qt] += rscomb[wq * 128 + qt * 64 + l];
      // reduce k-partials across lg (lane bits 4,5)
      rs[qt] += __shfl_xor(rs[qt], 16);
      rs[qt] += __shfl_xor(rs[qt], 32);
    }
    float* ob = out + (size_t)b * CINT * NN;
    #pragma unroll
    for (int qt = 0; qt < 2; ++qt) {
      f4 rsi;
      #pragma unroll
      for (int r = 0; r < 4; ++r)
        rsi[r] = 1.0f / __shfl(rs[qt], lg * 4 + r, 64);
      #pragma unroll
      for (int dt = 0; dt < 8; ++dt) {
        f4 v = y[qt][dt] * rsi;
        *(float4*)&ob[(size_t)(dt * 16 + lr) * NN + qw + qt * 16 + lg * 4] = *(float4*)&v;
      }
    }
  }
}

extern "C" void kernel_launch(void* const* d_in, const int* in_sizes, int n_in,
                              void* d_out, int out_size, void* d_ws, size_t ws_size,
                              hipStream_t stream) {
  const float* x   = (const float*)d_in[0];
  const float* wth = (const float*)d_in[1];
  const float* bth = (const float*)d_in[2];
  const float* wph = (const float*)d_in[3];
  const float* bph = (const float*)d_in[4];
  const float* wg  = (const float*)d_in[5];
  const float* bg  = (const float*)d_in[6];
  float* out = (float*)d_out;

  u16* theta = (u16*)d_ws;
  u16* phiT  = theta + (size_t)B_ * NN * CINT;
  u16* gTt   = phiT  + (size_t)B_ * NN * CINT;

  dim3 gproj(64, 8), bproj(256);
  hipLaunchKernelGGL(proj_kernel, gproj, bproj, 0, stream,
                     x, wth, bth, wph, bph, wg, bg, theta, phiT, gTt);
  dim3 gattn(32, 8), battn(512);
  hipLaunchKernelGGL(attn_kernel, gattn, battn, 0, stream, theta, phiT, gTt, out);
}

// Round 4
// 142.231 us; speedup vs baseline: 4.1924x; 1.0133x over previous
//
#include <hip/hip_runtime.h>

typedef __attribute__((ext_vector_type(8))) short bf8;
typedef __attribute__((ext_vector_type(4))) float f4;
typedef unsigned short u16;

constexpr int B_ = 8, CIN = 256, CINT = 128, NN = 4096;
constexpr float L2E = 1.44269504088896f;

__device__ __forceinline__ u16 f2bf(float f) {
  unsigned int u = __builtin_bit_cast(unsigned int, f);
  u += 0x7FFFu + ((u >> 16) & 1u);   // round-to-nearest-even
  return (u16)(u >> 16);
}

__device__ __forceinline__ void glds16(const void* g, void* l) {
  __builtin_amdgcn_global_load_lds(
      (const __attribute__((address_space(1))) unsigned int*)g,
      (__attribute__((address_space(3))) unsigned int*)l, 16, 0, 0);
}

// ---------------- prep: f32 weights -> bf16 [mat][128][256]
__global__ __launch_bounds__(256) void prep_kernel(
    const float* __restrict__ wth, const float* __restrict__ wph,
    const float* __restrict__ wg, u16* __restrict__ wbf)
{
  int i = blockIdx.x * 256 + threadIdx.x;          // 0..98303
  const float* src = (i < 32768) ? wth : (i < 65536) ? wph : wg;
  wbf[i] = f2bf(src[i & 32767]);
}

// ---------------- proj:
// theta [b][n][128] bf16 row-major.
// phiT  tiled [b][kt=n/32][r=n%32][128d], 16B chunks swizzled c16 ^= (r&7).
// gTt   tiled [b][kt=n/32][d][32k],      16B chunks swizzled c16 ^= (d&3).
__global__ __launch_bounds__(256) void proj_kernel(
    const float* __restrict__ x, const u16* __restrict__ wbf,
    const float* __restrict__ bth, const float* __restrict__ bph,
    const float* __restrict__ bg,
    u16* __restrict__ theta, u16* __restrict__ phiT, u16* __restrict__ gTt)
{
  const int b = blockIdx.y, n0 = blockIdx.x * 64;
  const int tid = threadIdx.x, w = tid >> 6, l = tid & 63;
  const int lr = l & 15, lg = l >> 4;
  __shared__ __align__(16) u16 sx[64 * 256];       // [n][c], swizzled, 32KB

  // stage x-tile: convert f32->bf16 once, transposed to [n][c], coalesced reads
  const float* xb = x + (size_t)b * CIN * NN + n0;
  #pragma unroll
  for (int pass = 0; pass < 8; ++pass) {
    const int cb = w * 8 + pass * 32;
    u16 tmp[8];
    #pragma unroll
    for (int i = 0; i < 8; ++i) tmp[i] = f2bf(xb[(size_t)(cb + i) * NN + l]);
    uint4 v;
    v.x = (unsigned)tmp[0] | ((unsigned)tmp[1] << 16);
    v.y = (unsigned)tmp[2] | ((unsigned)tmp[3] << 16);
    v.z = (unsigned)tmp[4] | ((unsigned)tmp[5] << 16);
    v.w = (unsigned)tmp[6] | ((unsigned)tmp[7] << 16);
    *(uint4*)&sx[l * 256 + (((w + pass * 4) ^ (l & 7)) << 3)] = v;
  }
  __syncthreads();

  #pragma unroll
  for (int dti = 0; dti < 6; ++dti) {
    const int dt = w * 6 + dti;                    // 24 d-tiles over 3 mats
    const int mat = dt >> 3, d0 = (dt & 7) * 16;
    const float* Bv = (mat == 0) ? bth : (mat == 1) ? bph : bg;
    const u16* wrow = wbf + mat * 32768 + (size_t)(d0 + lr) * 256 + lg * 8;
    bf8 wf[8];
    #pragma unroll
    for (int ks = 0; ks < 8; ++ks) wf[ks] = *(const bf8*)(wrow + ks * 32);

    #pragma unroll
    for (int mt = 0; mt < 4; ++mt) {
      f4 acc = {0.f, 0.f, 0.f, 0.f};
      const int row = mt * 16 + lr;
      #pragma unroll
      for (int ks = 0; ks < 8; ++ks) {
        bf8 bx = *(const bf8*)&sx[row * 256 + (((ks * 4 + lg) ^ (lr & 7)) << 3)];
        acc = __builtin_amdgcn_mfma_f32_16x16x32_bf16(wf[ks], bx, acc, 0, 0, 0);
      }
      const int m = n0 + mt * 16 + lr;             // n index
      const int dlo = d0 + lg * 4;
      if (mat == 0) {
        ushort4 h4;
        h4.x = f2bf(acc[0] + Bv[dlo + 0]);
        h4.y = f2bf(acc[1] + Bv[dlo + 1]);
        h4.z = f2bf(acc[2] + Bv[dlo + 2]);
        h4.w = f2bf(acc[3] + Bv[dlo + 3]);
        *(ushort4*)&theta[((size_t)b * NN + m) * CINT + dlo] = h4;
      } else if (mat == 1) {
        const int kt = m >> 5, r32 = m & 31;
        ushort4 h4;
        h4.x = f2bf((acc[0] + Bv[dlo + 0]) * L2E);
        h4.y = f2bf((acc[1] + Bv[dlo + 1]) * L2E);
        h4.z = f2bf((acc[2] + Bv[dlo + 2]) * L2E);
        h4.w = f2bf((acc[3] + Bv[dlo + 3]) * L2E);
        *(ushort4*)&phiT[((size_t)(b * 128 + kt)) * 4096 + r32 * 128 +
                         ((((dlo >> 3) ^ (r32 & 7))) << 3) + (dlo & 7)] = h4;
      } else {
        const int kt = m >> 5, kk = m & 31;
        #pragma unroll
        for (int r = 0; r < 4; ++r) {
          const int d = dlo + r;
          gTt[((size_t)(b * 128 + kt)) * 4096 + d * 32 +
              (((kk >> 3) ^ (d & 3)) << 3) + (kk & 7)] = f2bf(acc[r] + Bv[d]);
        }
      }
    }
  }
}

// ---------------- attn: 8 waves = 4 q-waves x 2 k-halves; 16 q/wave, KT=32.
// phi/g staged via global_load_lds (linear copy of pre-swizzled tiles), dbuf.
__global__ __launch_bounds__(512) void attn_kernel(
    const u16* __restrict__ theta, const u16* __restrict__ phiT,
    const u16* __restrict__ gTt, float* __restrict__ out)
{
  const int b = blockIdx.y;
  const int tid = threadIdx.x, w = tid >> 6, l = tid & 63;
  const int lr = l & 15, lg = l >> 4;
  const int qw = w & 3, h = w >> 2;
  const int qblk = blockIdx.x * 64;

  __shared__ __align__(16) u16 sphi[2][2][32 * 128];  // [h][buf] 8KB tiles
  __shared__ __align__(16) u16 sg[2][2][128 * 32];
  __shared__ __align__(16) u16 sP[8][16 * 32];        // per-wave 1KB

  // theta fragments (B-operand of swapped QK^T)
  const u16* th = theta + ((size_t)b * NN + qblk + qw * 16) * CINT;
  bf8 qf[4];
  #pragma unroll
  for (int ds = 0; ds < 4; ++ds)
    qf[ds] = *(const bf8*)(th + (size_t)lr * CINT + ds * 32 + lg * 8);

  f4 y[8];
  #pragma unroll
  for (int dt = 0; dt < 8; ++dt) y[dt] = (f4){0.f, 0.f, 0.f, 0.f};
  float rs = 0.f;

  const char* pph = (const char*)(phiT + ((size_t)(b * 128 + h * 64)) * 4096) +
                    qw * 2048 + l * 16;
  const char* pgg = (const char*)(gTt + ((size_t)(b * 128 + h * 64)) * 4096) +
                    qw * 2048 + l * 16;

  #define STAGE(BUF)                                                   \
    {                                                                  \
      char* lp = (char*)&sphi[h][BUF][0] + qw * 2048;                  \
      glds16(pph, lp); glds16(pph + 1024, lp + 1024);                  \
      char* lq = (char*)&sg[h][BUF][0] + qw * 2048;                    \
      glds16(pgg, lq); glds16(pgg + 1024, lq + 1024);                  \
      pph += 8192; pgg += 8192;                                        \
    }

  STAGE(0);
  __syncthreads();
  int cur = 0;

  const int sof = (lg ^ (lr & 3)) << 3;   // shared 16B-chunk swizzle offset (P,g)
  for (int t = 0; t < 64; ++t) {
    if (t < 63) STAGE(cur ^ 1);

    // ---- swapped QK^T: A = phi (k rows), B = theta (q rows)
    f4 s0 = {0.f, 0.f, 0.f, 0.f}, s1 = {0.f, 0.f, 0.f, 0.f};
    __builtin_amdgcn_s_setprio(1);
    #pragma unroll
    for (int ds = 0; ds < 4; ++ds) {
      const int co = ((ds * 4 + lg) ^ (lr & 7)) << 3;
      bf8 a0 = *(const bf8*)&sphi[h][cur][lr * 128 + co];
      bf8 a1 = *(const bf8*)&sphi[h][cur][(16 + lr) * 128 + co];
      s0 = __builtin_amdgcn_mfma_f32_16x16x32_bf16(a0, qf[ds], s0, 0, 0, 0);
      s1 = __builtin_amdgcn_mfma_f32_16x16x32_bf16(a1, qf[ds], s1, 0, 0, 0);
    }
    __builtin_amdgcn_s_setprio(0);

    // ---- exp2 (phi pre-scaled by log2e), rowsum partial, pack P
    float p0 = __builtin_amdgcn_exp2f(s0[0]), p1 = __builtin_amdgcn_exp2f(s0[1]);
    float p2 = __builtin_amdgcn_exp2f(s0[2]), p3 = __builtin_amdgcn_exp2f(s0[3]);
    float p4 = __builtin_amdgcn_exp2f(s1[0]), p5 = __builtin_amdgcn_exp2f(s1[1]);
    float p6 = __builtin_amdgcn_exp2f(s1[2]), p7 = __builtin_amdgcn_exp2f(s1[3]);
    rs += ((p0 + p1) + (p2 + p3)) + ((p4 + p5) + (p6 + p7));
    ushort4 pk;
    pk.x = f2bf(p0); pk.y = f2bf(p1); pk.z = f2bf(p2); pk.w = f2bf(p3);
    *(ushort4*)&sP[w][lr * 32 + (((lg >> 1) ^ (lr & 3)) << 3) + ((lg & 1) << 2)] = pk;
    pk.x = f2bf(p4); pk.y = f2bf(p5); pk.z = f2bf(p6); pk.w = f2bf(p7);
    *(ushort4*)&sP[w][lr * 32 + (((2 + (lg >> 1)) ^ (lr & 3)) << 3) + ((lg & 1) << 2)] = pk;

    // ---- PV: A = P (q rows), B = g (d rows)
    bf8 paf = *(const bf8*)&sP[w][lr * 32 + sof];
    __builtin_amdgcn_s_setprio(1);
    #pragma unroll
    for (int dt = 0; dt < 8; ++dt) {
      bf8 gf = *(const bf8*)&sg[h][cur][(dt * 16 + lr) * 32 + sof];
      y[dt] = __builtin_amdgcn_mfma_f32_16x16x32_bf16(paf, gf, y[dt], 0, 0, 0);
    }
    __builtin_amdgcn_s_setprio(0);

    __syncthreads();
    cur ^= 1;
  }

  // ---- combine k-halves through LDS (tiles dead; loop ended on a barrier)
  rs += __shfl_xor(rs, 16);
  rs += __shfl_xor(rs, 32);
  float* yc = (float*)&sphi[0][0][0];   // 32KB
  float* rc = (float*)&sP[0][0];
  if (h == 1) {
    #pragma unroll
    for (int dt = 0; dt < 8; ++dt)
      *(f4*)&yc[qw * 2048 + (dt * 16 + lr) * 16 + lg * 4] = y[dt];
    if (lg == 0) rc[qw * 16 + lr] = rs;
  }
  __syncthreads();
  if (h == 0) {
    rs += rc[qw * 16 + lr];
    f4 rsi;
    #pragma unroll
    for (int r = 0; r < 4; ++r) rsi[r] = 1.0f / __shfl(rs, lg * 4 + r, 64);
    float* ob = out + (size_t)b * CINT * NN + qblk + qw * 16;
    #pragma unroll
    for (int dt = 0; dt < 8; ++dt) {
      f4 v = (y[dt] + *(const f4*)&yc[qw * 2048 + (dt * 16 + lr) * 16 + lg * 4]) * rsi;
      *(float4*)&ob[(size_t)(dt * 16 + lr) * NN + lg * 4] = *(float4*)&v;
    }
  }
}

extern "C" void kernel_launch(void* const* d_in, const int* in_sizes, int n_in,
                              void* d_out, int out_size, void* d_ws, size_t ws_size,
                              hipStream_t stream) {
  const float* x   = (const float*)d_in[0];
  const float* wth = (const float*)d_in[1];
  const float* bth = (const float*)d_in[2];
  const float* wph = (const float*)d_in[3];
  const float* bph = (const float*)d_in[4];
  const float* wg  = (const float*)d_in[5];
  const float* bg  = (const float*)d_in[6];
  float* out = (float*)d_out;

  u16* theta = (u16*)d_ws;
  u16* phiT  = theta + (size_t)B_ * NN * CINT;
  u16* gTt   = phiT  + (size_t)B_ * NN * CINT;
  u16* wbf   = gTt   + (size_t)B_ * NN * CINT;

  hipLaunchKernelGGL(prep_kernel, dim3(384), dim3(256), 0, stream, wth, wph, wg, wbf);
  hipLaunchKernelGGL(proj_kernel, dim3(64, 8), dim3(256), 0, stream,
                     x, wbf, bth, bph, bg, theta, phiT, gTt);
  hipLaunchKernelGGL(attn_kernel, dim3(64, 8), dim3(512), 0, stream,
                     theta, phiT, gTt, out);
}

// Round 5
// 123.674 us; speedup vs baseline: 4.8215x; 1.1501x over previous
//
#include <hip/hip_runtime.h>

typedef __attribute__((ext_vector_type(8))) short bf8;
typedef __attribute__((ext_vector_type(4))) float f4;
typedef unsigned short u16;

constexpr int B_ = 8, CIN = 256, CINT = 128, NN = 4096;
constexpr float L2E = 1.44269504088896f;

__device__ __forceinline__ u16 f2bf(float f) {
  unsigned int u = __builtin_bit_cast(unsigned int, f);
  u += 0x7FFFu + ((u >> 16) & 1u);   // round-to-nearest-even
  return (u16)(u >> 16);
}

__device__ __forceinline__ void glds16(const void* g, void* l) {
  __builtin_amdgcn_global_load_lds(
      (const __attribute__((address_space(1))) unsigned int*)g,
      (__attribute__((address_space(3))) unsigned int*)l, 16, 0, 0);
}

// ---------------- prep: f32 weights -> bf16 [mat][128][256]
__global__ __launch_bounds__(256) void prep_kernel(
    const float* __restrict__ wth, const float* __restrict__ wph,
    const float* __restrict__ wg, u16* __restrict__ wbf)
{
  int i = blockIdx.x * 256 + threadIdx.x;          // 0..98303
  const float* src = (i < 32768) ? wth : (i < 65536) ? wph : wg;
  wbf[i] = f2bf(src[i & 32767]);
}

// ---------------- proj:
// theta [b][n][128] bf16 row-major.
// phiT  tiled [b][kt=n/64][r=n%64][128d], 16B chunks swizzled c16 ^= (r&7),
//       values pre-scaled by log2(e).
// gTt   tiled [b][kt=n/64][d][64k],      16B chunks swizzled c16 ^= (d&7).
__global__ __launch_bounds__(256) void proj_kernel(
    const float* __restrict__ x, const u16* __restrict__ wbf,
    const float* __restrict__ bth, const float* __restrict__ bph,
    const float* __restrict__ bg,
    u16* __restrict__ theta, u16* __restrict__ phiT, u16* __restrict__ gTt)
{
  const int b = blockIdx.y, n0 = blockIdx.x * 64;
  const int tid = threadIdx.x, w = tid >> 6, l = tid & 63;
  const int lr = l & 15, lg = l >> 4;
  __shared__ __align__(16) u16 sx[64 * 256];       // [n][c], swizzled, 32KB

  // stage x-tile: convert f32->bf16 once, transposed to [n][c], coalesced reads
  const float* xb = x + (size_t)b * CIN * NN + n0;
  #pragma unroll
  for (int pass = 0; pass < 8; ++pass) {
    const int cb = w * 8 + pass * 32;
    u16 tmp[8];
    #pragma unroll
    for (int i = 0; i < 8; ++i) tmp[i] = f2bf(xb[(size_t)(cb + i) * NN + l]);
    uint4 v;
    v.x = (unsigned)tmp[0] | ((unsigned)tmp[1] << 16);
    v.y = (unsigned)tmp[2] | ((unsigned)tmp[3] << 16);
    v.z = (unsigned)tmp[4] | ((unsigned)tmp[5] << 16);
    v.w = (unsigned)tmp[6] | ((unsigned)tmp[7] << 16);
    *(uint4*)&sx[l * 256 + (((w + pass * 4) ^ (l & 7)) << 3)] = v;
  }
  __syncthreads();

  #pragma unroll
  for (int dti = 0; dti < 6; ++dti) {
    const int dt = w * 6 + dti;                    // 24 d-tiles over 3 mats
    const int mat = dt >> 3, d0 = (dt & 7) * 16;
    const float* Bv = (mat == 0) ? bth : (mat == 1) ? bph : bg;
    const u16* wrow = wbf + mat * 32768 + (size_t)(d0 + lr) * 256 + lg * 8;
    bf8 wf[8];
    #pragma unroll
    for (int ks = 0; ks < 8; ++ks) wf[ks] = *(const bf8*)(wrow + ks * 32);

    #pragma unroll
    for (int mt = 0; mt < 4; ++mt) {
      f4 acc = {0.f, 0.f, 0.f, 0.f};
      const int row = mt * 16 + lr;
      #pragma unroll
      for (int ks = 0; ks < 8; ++ks) {
        bf8 bx = *(const bf8*)&sx[row * 256 + (((ks * 4 + lg) ^ (lr & 7)) << 3)];
        acc = __builtin_amdgcn_mfma_f32_16x16x32_bf16(wf[ks], bx, acc, 0, 0, 0);
      }
      const int m = n0 + mt * 16 + lr;             // n index
      const int dlo = d0 + lg * 4;
      if (mat == 0) {
        ushort4 h4;
        h4.x = f2bf(acc[0] + Bv[dlo + 0]);
        h4.y = f2bf(acc[1] + Bv[dlo + 1]);
        h4.z = f2bf(acc[2] + Bv[dlo + 2]);
        h4.w = f2bf(acc[3] + Bv[dlo + 3]);
        *(ushort4*)&theta[((size_t)b * NN + m) * CINT + dlo] = h4;
      } else if (mat == 1) {
        const int kt = m >> 6, rr = m & 63;
        ushort4 h4;
        h4.x = f2bf((acc[0] + Bv[dlo + 0]) * L2E);
        h4.y = f2bf((acc[1] + Bv[dlo + 1]) * L2E);
        h4.z = f2bf((acc[2] + Bv[dlo + 2]) * L2E);
        h4.w = f2bf((acc[3] + Bv[dlo + 3]) * L2E);
        *(ushort4*)&phiT[((size_t)(b * 64 + kt)) * 8192 + rr * 128 +
                         ((((dlo >> 3) ^ (rr & 7))) << 3) + (dlo & 7)] = h4;
      } else {
        const int kt = m >> 6, rr = m & 63;
        #pragma unroll
        for (int r = 0; r < 4; ++r) {
          const int d = dlo + r;
          gTt[((size_t)(b * 64 + kt)) * 8192 + d * 64 +
              (((rr >> 3) ^ (d & 7)) << 3) + (rr & 7)] = f2bf(acc[r] + Bv[d]);
        }
      }
    }
  }
}

// ---------------- attn: 8 waves = 4 q-waves (32 q each) x 2 k-halves; KT=64.
// phi/g staged via global_load_lds (linear DMA of pre-swizzled tiles), dbuf.
__global__ __launch_bounds__(512, 2) void attn_kernel(
    const u16* __restrict__ theta, const u16* __restrict__ phiT,
    const u16* __restrict__ gTt, float* __restrict__ out)
{
  const int b  = blockIdx.y;
  const int t_ = threadIdx.x;
  const int w  = t_ >> 6;
  const int l  = t_ & 63;
  const int lr = l & 15, lg = l >> 4;
  const int h  = w >> 2, wq = w & 3;
  const int qw = blockIdx.x * 128 + wq * 32;

  __shared__ __align__(16) u16 sphi[2][2][64 * 128];  // [half][buf] 16KB tiles
  __shared__ __align__(16) u16 sg[2][2][128 * 64];
  __shared__ __align__(16) u16 sP[8][16 * 64];        // per-wave, reused per qt

  const u16* th = theta + (size_t)b * NN * CINT;

  // theta fragments (B-operand of swapped QK^T), resident in regs
  bf8 qf[2][4];
  #pragma unroll
  for (int qt = 0; qt < 2; ++qt)
    #pragma unroll
    for (int ds = 0; ds < 4; ++ds)
      qf[qt][ds] = *(const bf8*)(th + (size_t)(qw + qt * 16 + lr) * CINT + ds * 32 + lg * 8);

  f4 y[2][8];
  #pragma unroll
  for (int qt = 0; qt < 2; ++qt)
    #pragma unroll
    for (int dt = 0; dt < 8; ++dt) y[qt][dt] = (f4){0.f, 0.f, 0.f, 0.f};
  float rs[2] = {0.f, 0.f};

  // staging pointers: each wave copies its 4KB quarter of both 16KB tiles
  const char* pph = (const char*)(phiT + (size_t)(b * 64 + h * 32) * 8192) +
                    wq * 4096 + l * 16;
  const char* pgg = (const char*)(gTt + (size_t)(b * 64 + h * 32) * 8192) +
                    wq * 4096 + l * 16;

  #define STAGE(BUF)                                                     \
    {                                                                    \
      char* lp = (char*)&sphi[h][BUF][0] + wq * 4096;                    \
      char* lq = (char*)&sg[h][BUF][0] + wq * 4096;                      \
      glds16(pph, lp);        glds16(pph + 1024, lp + 1024);             \
      glds16(pph + 2048, lp + 2048); glds16(pph + 3072, lp + 3072);      \
      glds16(pgg, lq);        glds16(pgg + 1024, lq + 1024);             \
      glds16(pgg + 2048, lq + 2048); glds16(pgg + 3072, lq + 3072);      \
      pph += 16384; pgg += 16384;                                        \
    }

  STAGE(0);
  __syncthreads();
  int cur = 0;

  for (int t = 0; t < 32; ++t) {
    if (t < 31) STAGE(cur ^ 1);

    // ---- swapped QK^T: S^T tiles; A = phi rows (k), B = theta rows (q)
    f4 s[2][4];
    #pragma unroll
    for (int qt = 0; qt < 2; ++qt)
      #pragma unroll
      for (int st = 0; st < 4; ++st) s[qt][st] = (f4){0.f, 0.f, 0.f, 0.f};
    __builtin_amdgcn_s_setprio(1);
    #pragma unroll
    for (int st = 0; st < 4; ++st) {
      const u16* base = &sphi[h][cur][(st * 16 + lr) * 128];
      #pragma unroll
      for (int ds = 0; ds < 4; ++ds) {
        bf8 af = *(const bf8*)(base + (((ds * 4 + lg) ^ (lr & 7)) * 8));
        #pragma unroll
        for (int qt = 0; qt < 2; ++qt)
          s[qt][st] = __builtin_amdgcn_mfma_f32_16x16x32_bf16(af, qf[qt][ds], s[qt][st], 0, 0, 0);
      }
    }
    __builtin_amdgcn_s_setprio(0);

    // ---- preload g fragments (shared across both qt passes)
    bf8 gfr[8][2];
    #pragma unroll
    for (int dt = 0; dt < 8; ++dt)
      #pragma unroll
      for (int ks = 0; ks < 2; ++ks)
        gfr[dt][ks] = *(const bf8*)&sg[h][cur][(dt * 16 + lr) * 64 + (((ks * 4 + lg) ^ (lr & 7)) * 8)];

    // ---- per-qt: exp2, pack b64 into sP, read P-fragments, PV MFMAs
    #pragma unroll
    for (int qt = 0; qt < 2; ++qt) {
      #pragma unroll
      for (int st = 0; st < 4; ++st) {
        float p0 = __builtin_amdgcn_exp2f(s[qt][st][0]);
        float p1 = __builtin_amdgcn_exp2f(s[qt][st][1]);
        float p2 = __builtin_amdgcn_exp2f(s[qt][st][2]);
        float p3 = __builtin_amdgcn_exp2f(s[qt][st][3]);
        rs[qt] += (p0 + p1) + (p2 + p3);
        ushort4 pk;
        pk.x = f2bf(p0); pk.y = f2bf(p1); pk.z = f2bf(p2); pk.w = f2bf(p3);
        *(ushort4*)&sP[w][lr * 64 + (((st * 2 + (lg >> 1)) ^ (lr & 7)) << 3) + ((lg & 1) << 2)] = pk;
      }
      bf8 paf[2];
      #pragma unroll
      for (int ks = 0; ks < 2; ++ks)
        paf[ks] = *(const bf8*)&sP[w][lr * 64 + ((((ks << 2) + lg) ^ (lr & 7)) << 3)];
      __builtin_amdgcn_s_setprio(1);
      #pragma unroll
      for (int dt = 0; dt < 8; ++dt) {
        y[qt][dt] = __builtin_amdgcn_mfma_f32_16x16x32_bf16(paf[0], gfr[dt][0], y[qt][dt], 0, 0, 0);
        y[qt][dt] = __builtin_amdgcn_mfma_f32_16x16x32_bf16(paf[1], gfr[dt][1], y[qt][dt], 0, 0, 0);
      }
      __builtin_amdgcn_s_setprio(0);
    }

    __syncthreads();
    cur ^= 1;
  }

  // ---- combine the two k-halves through LDS (tiles dead; loop ended on a barrier)
  float* ycomb  = (float*)&sphi[0][0][0];   // 64KB: 4 waves x 16KB
  float* rscomb = (float*)&sg[0][0][0];
  if (h == 1) {
    #pragma unroll
    for (int qt = 0; qt < 2; ++qt) {
      #pragma unroll
      for (int dt = 0; dt < 8; ++dt)
        *(f4*)&ycomb[wq * 4096 + (qt * 8 + dt) * 256 + l * 4] = y[qt][dt];
      rscomb[wq * 128 + qt * 64 + l] = rs[qt];
    }
  }
  __syncthreads();
  if (h == 0) {
    #pragma unroll
    for (int qt = 0; qt < 2; ++qt) {
      #pragma unroll
      for (int dt = 0; dt < 8; ++dt)
        y[qt][dt] += *(const f4*)&ycomb[wq * 4096 + (qt * 8 + dt) * 256 + l * 4];
      rs[qt] += rscomb[wq * 128 + qt * 64 + l];
      // reduce k-partials across lg (lane bits 4,5)
      rs[qt] += __shfl_xor(rs[qt], 16);
      rs[qt] += __shfl_xor(rs[qt], 32);
    }
    float* ob = out + (size_t)b * CINT * NN;
    #pragma unroll
    for (int qt = 0; qt < 2; ++qt) {
      f4 rsi;
      #pragma unroll
      for (int r = 0; r < 4; ++r)
        rsi[r] = 1.0f / __shfl(rs[qt], lg * 4 + r, 64);
      #pragma unroll
      for (int dt = 0; dt < 8; ++dt) {
        f4 v = y[qt][dt] * rsi;
        *(float4*)&ob[(size_t)(dt * 16 + lr) * NN + qw + qt * 16 + lg * 4] = *(float4*)&v;
      }
    }
  }
}

extern "C" void kernel_launch(void* const* d_in, const int* in_sizes, int n_in,
                              void* d_out, int out_size, void* d_ws, size_t ws_size,
                              hipStream_t stream) {
  const float* x   = (const float*)d_in[0];
  const float* wth = (const float*)d_in[1];
  const float* bth = (const float*)d_in[2];
  const float* wph = (const float*)d_in[3];
  const float* bph = (const float*)d_in[4];
  const float* wg  = (const float*)d_in[5];
  const float* bg  = (const float*)d_in[6];
  float* out = (float*)d_out;

  u16* theta = (u16*)d_ws;
  u16* phiT  = theta + (size_t)B_ * NN * CINT;
  u16* gTt   = phiT  + (size_t)B_ * NN * CINT;
  u16* wbf   = gTt   + (size_t)B_ * NN * CINT;

  hipLaunchKernelGGL(prep_kernel, dim3(384), dim3(256), 0, stream, wth, wph, wg, wbf);
  hipLaunchKernelGGL(proj_kernel, dim3(64, 8), dim3(256), 0, stream,
                     x, wbf, bth, bph, bg, theta, phiT, gTt);
  hipLaunchKernelGGL(attn_kernel, dim3(32, 8), dim3(512), 0, stream,
                     theta, phiT, gTt, out);
}

// Round 6
// 118.135 us; speedup vs baseline: 5.0475x; 1.0469x over previous
//
#include <hip/hip_runtime.h>

typedef __attribute__((ext_vector_type(8))) short bf8;
typedef __attribute__((ext_vector_type(4))) float f4;
typedef unsigned short u16;

constexpr int B_ = 8, CIN = 256, CINT = 128, NN = 4096;
constexpr float L2E = 1.44269504088896f;

__device__ __forceinline__ u16 f2bf(float f) {
  unsigned int u = __builtin_bit_cast(unsigned int, f);
  u += 0x7FFFu + ((u >> 16) & 1u);   // round-to-nearest-even
  return (u16)(u >> 16);
}

__device__ __forceinline__ void glds16(const void* g, void* l) {
  __builtin_amdgcn_global_load_lds(
      (const __attribute__((address_space(1))) unsigned int*)g,
      (__attribute__((address_space(3))) unsigned int*)l, 16, 0, 0);
}

// ---------------- prep: f32 weights -> bf16 [mat][128][256]
__global__ __launch_bounds__(256) void prep_kernel(
    const float* __restrict__ wth, const float* __restrict__ wph,
    const float* __restrict__ wg, u16* __restrict__ wbf)
{
  int i = blockIdx.x * 256 + threadIdx.x;          // 0..98303
  const float* src = (i < 32768) ? wth : (i < 65536) ? wph : wg;
  wbf[i] = f2bf(src[i & 32767]);
}

// ---------------- proj:
// theta [b][n][128] bf16 row-major.
// phiT  tiled [b][kt=n/32][r=n%32][128d], 16B chunks swizzled c16 ^= (r&7),
//       values pre-scaled by log2(e).
// gTt   tiled [b][kt=n/32][d][32k],      16B chunks swizzled c4 ^= (d&3).
__global__ __launch_bounds__(256) void proj_kernel(
    const float* __restrict__ x, const u16* __restrict__ wbf,
    const float* __restrict__ bth, const float* __restrict__ bph,
    const float* __restrict__ bg,
    u16* __restrict__ theta, u16* __restrict__ phiT, u16* __restrict__ gTt)
{
  const int b = blockIdx.y, n0 = blockIdx.x * 64;
  const int tid = threadIdx.x, w = tid >> 6, l = tid & 63;
  const int lr = l & 15, lg = l >> 4;
  __shared__ __align__(16) u16 sx[64 * 256];       // [n][c], swizzled, 32KB

  // stage x-tile: convert f32->bf16 once, transposed to [n][c], coalesced reads
  const float* xb = x + (size_t)b * CIN * NN + n0;
  #pragma unroll
  for (int pass = 0; pass < 8; ++pass) {
    const int cb = w * 8 + pass * 32;
    u16 tmp[8];
    #pragma unroll
    for (int i = 0; i < 8; ++i) tmp[i] = f2bf(xb[(size_t)(cb + i) * NN + l]);
    uint4 v;
    v.x = (unsigned)tmp[0] | ((unsigned)tmp[1] << 16);
    v.y = (unsigned)tmp[2] | ((unsigned)tmp[3] << 16);
    v.z = (unsigned)tmp[4] | ((unsigned)tmp[5] << 16);
    v.w = (unsigned)tmp[6] | ((unsigned)tmp[7] << 16);
    *(uint4*)&sx[l * 256 + (((w + pass * 4) ^ (l & 7)) << 3)] = v;
  }
  __syncthreads();

  #pragma unroll
  for (int dti = 0; dti < 6; ++dti) {
    const int dt = w * 6 + dti;                    // 24 d-tiles over 3 mats
    const int mat = dt >> 3, d0 = (dt & 7) * 16;
    const float* Bv = (mat == 0) ? bth : (mat == 1) ? bph : bg;
    const u16* wrow = wbf + mat * 32768 + (size_t)(d0 + lr) * 256 + lg * 8;
    bf8 wf[8];
    #pragma unroll
    for (int ks = 0; ks < 8; ++ks) wf[ks] = *(const bf8*)(wrow + ks * 32);

    #pragma unroll
    for (int mt = 0; mt < 4; ++mt) {
      f4 acc = {0.f, 0.f, 0.f, 0.f};
      const int row = mt * 16 + lr;
      #pragma unroll
      for (int ks = 0; ks < 8; ++ks) {
        bf8 bx = *(const bf8*)&sx[row * 256 + (((ks * 4 + lg) ^ (lr & 7)) << 3)];
        acc = __builtin_amdgcn_mfma_f32_16x16x32_bf16(wf[ks], bx, acc, 0, 0, 0);
      }
      const int m = n0 + mt * 16 + lr;             // n index
      const int dlo = d0 + lg * 4;
      if (mat == 0) {
        ushort4 h4;
        h4.x = f2bf(acc[0] + Bv[dlo + 0]);
        h4.y = f2bf(acc[1] + Bv[dlo + 1]);
        h4.z = f2bf(acc[2] + Bv[dlo + 2]);
        h4.w = f2bf(acc[3] + Bv[dlo + 3]);
        *(ushort4*)&theta[((size_t)b * NN + m) * CINT + dlo] = h4;
      } else if (mat == 1) {
        const int kt = m >> 5, r32 = m & 31;
        ushort4 h4;
        h4.x = f2bf((acc[0] + Bv[dlo + 0]) * L2E);
        h4.y = f2bf((acc[1] + Bv[dlo + 1]) * L2E);
        h4.z = f2bf((acc[2] + Bv[dlo + 2]) * L2E);
        h4.w = f2bf((acc[3] + Bv[dlo + 3]) * L2E);
        *(ushort4*)&phiT[((size_t)(b * 128 + kt)) * 4096 + r32 * 128 +
                         ((((dlo >> 3) ^ (r32 & 7))) << 3) + (dlo & 7)] = h4;
      } else {
        const int kt = m >> 5, kk = m & 31;
        #pragma unroll
        for (int r = 0; r < 4; ++r) {
          const int d = dlo + r;
          gTt[((size_t)(b * 128 + kt)) * 4096 + d * 32 +
              (((kk >> 3) ^ (d & 3)) << 3) + (kk & 7)] = f2bf(acc[r] + Bv[d]);
        }
      }
    }
  }
}

// ---------------- attn: 8 waves = 4 q-waves (32 q) x 2 k-halves; KT=32.
// 3-buffer 2-deep glds16 pipeline, raw s_barrier + counted vmcnt (never 0
// in steady state).
__global__ __launch_bounds__(512, 2) void attn_kernel(
    const u16* __restrict__ theta, const u16* __restrict__ phiT,
    const u16* __restrict__ gTt, float* __restrict__ out)
{
  const int b  = blockIdx.y;
  const int t_ = threadIdx.x;
  const int w  = t_ >> 6;
  const int l  = t_ & 63;
  const int lr = l & 15, lg = l >> 4;
  const int h  = w >> 2, wq = w & 3;
  const int qw = blockIdx.x * 128 + wq * 32;

  // LDS carve: phi 2h x 3buf x 8KB | g same | sP 8 x 1KB  = 104KB
  __shared__ __align__(16) char smem[106496];
  u16* sphi_base = (u16*)smem;                    // (h*3+buf)*4096 u16
  u16* sg_base   = (u16*)(smem + 49152);
  u16* sPw       = (u16*)(smem + 98304 + w * 1024);

  const u16* th = theta + (size_t)b * NN * CINT;
  // theta fragments (B-operand of swapped QK^T), resident in regs
  bf8 qf[2][4];
  #pragma unroll
  for (int qt = 0; qt < 2; ++qt)
    #pragma unroll
    for (int ds = 0; ds < 4; ++ds)
      qf[qt][ds] = *(const bf8*)(th + (size_t)(qw + qt * 16 + lr) * CINT + ds * 32 + lg * 8);

  f4 y[2][8];
  #pragma unroll
  for (int qt = 0; qt < 2; ++qt)
    #pragma unroll
    for (int dt = 0; dt < 8; ++dt) y[qt][dt] = (f4){0.f, 0.f, 0.f, 0.f};
  float rs[2] = {0.f, 0.f};

  const char* psrc = (const char*)(phiT + (size_t)(b * 128 + h * 64) * 4096);
  const char* gsrc = (const char*)(gTt + (size_t)(b * 128 + h * 64) * 4096);

  // each wave stages its 2KB quarter of the 8KB phi and g tiles
  #define STAGE(BUF, T)                                                  \
    {                                                                    \
      const char* sp = psrc + (size_t)(T) * 8192 + wq * 2048 + l * 16;   \
      const char* sq = gsrc + (size_t)(T) * 8192 + wq * 2048 + l * 16;   \
      char* lp = (char*)(sphi_base + (h * 3 + (BUF)) * 4096) + wq * 2048;\
      char* lq = (char*)(sg_base + (h * 3 + (BUF)) * 4096) + wq * 2048;  \
      glds16(sp, lp); glds16(sp + 1024, lp + 1024);                      \
      glds16(sq, lq); glds16(sq + 1024, lq + 1024);                      \
    }

  constexpr int NT = 64;
  STAGE(0, 0);
  STAGE(1, 1);

  int bc = 0, bs = 2;    // current buf, stage buf (mod 3)
  for (int t = 0; t < NT; ++t) {
    if (t == NT - 1) asm volatile("s_waitcnt vmcnt(0)" ::: "memory");
    else             asm volatile("s_waitcnt vmcnt(4)" ::: "memory");
    __builtin_amdgcn_s_barrier();
    __builtin_amdgcn_sched_barrier(0);

    if (t < NT - 2) STAGE(bs, t + 2);

    const u16* PH = sphi_base + (h * 3 + bc) * 4096;
    const u16* GG = sg_base + (h * 3 + bc) * 4096;

    // ---- swapped QK^T: A = phi (k rows), B = theta (q rows)
    f4 s[2][2];
    s[0][0] = (f4){0.f,0.f,0.f,0.f}; s[0][1] = (f4){0.f,0.f,0.f,0.f};
    s[1][0] = (f4){0.f,0.f,0.f,0.f}; s[1][1] = (f4){0.f,0.f,0.f,0.f};
    __builtin_amdgcn_s_setprio(1);
    #pragma unroll
    for (int st = 0; st < 2; ++st) {
      const u16* base = PH + (st * 16 + lr) * 128;
      #pragma unroll
      for (int ds = 0; ds < 4; ++ds) {
        bf8 af = *(const bf8*)(base + (((ds * 4 + lg) ^ (lr & 7)) << 3));
        s[0][st] = __builtin_amdgcn_mfma_f32_16x16x32_bf16(af, qf[0][ds], s[0][st], 0, 0, 0);
        s[1][st] = __builtin_amdgcn_mfma_f32_16x16x32_bf16(af, qf[1][ds], s[1][st], 0, 0, 0);
      }
    }
    __builtin_amdgcn_s_setprio(0);

    // ---- g fragments (shared across both qt passes)
    bf8 gfr[8];
    #pragma unroll
    for (int dt = 0; dt < 8; ++dt)
      gfr[dt] = *(const bf8*)(GG + (dt * 16 + lr) * 32 + ((lg ^ (lr & 3)) << 3));

    // ---- per qt: exp2, pack into sP, read P-frag, PV
    #pragma unroll
    for (int qt = 0; qt < 2; ++qt) {
      float p0 = __builtin_amdgcn_exp2f(s[qt][0][0]);
      float p1 = __builtin_amdgcn_exp2f(s[qt][0][1]);
      float p2 = __builtin_amdgcn_exp2f(s[qt][0][2]);
      float p3 = __builtin_amdgcn_exp2f(s[qt][0][3]);
      float p4 = __builtin_amdgcn_exp2f(s[qt][1][0]);
      float p5 = __builtin_amdgcn_exp2f(s[qt][1][1]);
      float p6 = __builtin_amdgcn_exp2f(s[qt][1][2]);
      float p7 = __builtin_amdgcn_exp2f(s[qt][1][3]);
      rs[qt] += ((p0 + p1) + (p2 + p3)) + ((p4 + p5) + (p6 + p7));
      ushort4 pk;
      pk.x = f2bf(p0); pk.y = f2bf(p1); pk.z = f2bf(p2); pk.w = f2bf(p3);
      *(ushort4*)&sPw[lr * 32 + (((lg >> 1) ^ (lr & 3)) << 3) + ((lg & 1) << 2)] = pk;
      pk.x = f2bf(p4); pk.y = f2bf(p5); pk.z = f2bf(p6); pk.w = f2bf(p7);
      *(ushort4*)&sPw[lr * 32 + (((2 + (lg >> 1)) ^ (lr & 3)) << 3) + ((lg & 1) << 2)] = pk;

      bf8 paf = *(const bf8*)&sPw[lr * 32 + ((lg ^ (lr & 3)) << 3)];
      __builtin_amdgcn_s_setprio(1);
      #pragma unroll
      for (int dt = 0; dt < 8; ++dt)
        y[qt][dt] = __builtin_amdgcn_mfma_f32_16x16x32_bf16(paf, gfr[dt], y[qt][dt], 0, 0, 0);
      __builtin_amdgcn_s_setprio(0);
    }

    bc = (bc == 2) ? 0 : bc + 1;
    bs = (bs == 2) ? 0 : bs + 1;
  }

  // ---- combine the two k-halves through LDS (all tiles dead)
  #pragma unroll
  for (int qt = 0; qt < 2; ++qt) {
    rs[qt] += __shfl_xor(rs[qt], 16);
    rs[qt] += __shfl_xor(rs[qt], 32);
  }
  __syncthreads();
  float* ycomb  = (float*)smem;            // 64KB
  float* rscomb = (float*)(smem + 65536);  // 2KB
  if (h == 1) {
    #pragma unroll
    for (int qt = 0; qt < 2; ++qt) {
      #pragma unroll
      for (int dt = 0; dt < 8; ++dt)
        *(f4*)&ycomb[wq * 4096 + (qt * 8 + dt) * 256 + l * 4] = y[qt][dt];
      rscomb[wq * 128 + qt * 64 + l] = rs[qt];
    }
  }
  __syncthreads();
  if (h == 0) {
    #pragma unroll
    for (int qt = 0; qt < 2; ++qt) {
      #pragma unroll
      for (int dt = 0; dt < 8; ++dt)
        y[qt][dt] += *(const f4*)&ycomb[wq * 4096 + (qt * 8 + dt) * 256 + l * 4];
      rs[qt] += rscomb[wq * 128 + qt * 64 + l];
    }
    float* ob = out + (size_t)b * CINT * NN;
    #pragma unroll
    for (int qt = 0; qt < 2; ++qt) {
      f4 rsi;
      #pragma unroll
      for (int r = 0; r < 4; ++r)
        rsi[r] = 1.0f / __shfl(rs[qt], lg * 4 + r, 64);
      #pragma unroll
      for (int dt = 0; dt < 8; ++dt) {
        f4 v = y[qt][dt] * rsi;
        *(float4*)&ob[(size_t)(dt * 16 + lr) * NN + qw + qt * 16 + lg * 4] = *(float4*)&v;
      }
    }
  }
}

extern "C" void kernel_launch(void* const* d_in, const int* in_sizes, int n_in,
                              void* d_out, int out_size, void* d_ws, size_t ws_size,
                              hipStream_t stream) {
  const float* x   = (const float*)d_in[0];
  const float* wth = (const float*)d_in[1];
  const float* bth = (const float*)d_in[2];
  const float* wph = (const float*)d_in[3];
  const float* bph = (const float*)d_in[4];
  const float* wg  = (const float*)d_in[5];
  const float* bg  = (const float*)d_in[6];
  float* out = (float*)d_out;

  u16* theta = (u16*)d_ws;
  u16* phiT  = theta + (size_t)B_ * NN * CINT;
  u16* gTt   = phiT  + (size_t)B_ * NN * CINT;
  u16* wbf   = gTt   + (size_t)B_ * NN * CINT;

  hipLaunchKernelGGL(prep_kernel, dim3(384), dim3(256), 0, stream, wth, wph, wg, wbf);
  hipLaunchKernelGGL(proj_kernel, dim3(64, 8), dim3(256), 0, stream,
                     x, wbf, bth, bph, bg, theta, phiT, gTt);
  hipLaunchKernelGGL(attn_kernel, dim3(32, 8), dim3(512), 0, stream,
                     theta, phiT, gTt, out);
}

// Round 7
// 104.667 us; speedup vs baseline: 5.6970x; 1.1287x over previous
//
#include <hip/hip_runtime.h>

typedef __attribute__((ext_vector_type(8))) short bf8;
typedef __attribute__((ext_vector_type(4))) float f4;
typedef unsigned short u16;

constexpr int B_ = 8, CIN = 256, CINT = 128, NN = 4096;
constexpr float L2E = 1.44269504088896f;

__device__ __forceinline__ u16 f2bf(float f) {
  unsigned int u = __builtin_bit_cast(unsigned int, f);
  u += 0x7FFFu + ((u >> 16) & 1u);   // round-to-nearest-even
  return (u16)(u >> 16);
}

__device__ __forceinline__ void glds16(const void* g, void* l) {
  __builtin_amdgcn_global_load_lds(
      (const __attribute__((address_space(1))) unsigned int*)g,
      (__attribute__((address_space(3))) unsigned int*)l, 16, 0, 0);
}

// pack two f32 -> one u32 of 2 bf16 (RTNE)
__device__ __forceinline__ int cvtpk(float lo, float hi) {
  int r;
  asm("v_cvt_pk_bf16_f32 %0, %1, %2" : "=v"(r) : "v"(lo), "v"(hi));
  return r;
}

// ---------------- prep: f32 weights -> bf16 [mat][128][256]
__global__ __launch_bounds__(256) void prep_kernel(
    const float* __restrict__ wth, const float* __restrict__ wph,
    const float* __restrict__ wg, u16* __restrict__ wbf)
{
  int i = blockIdx.x * 256 + threadIdx.x;          // 0..98303
  const float* src = (i < 32768) ? wth : (i < 65536) ? wph : wg;
  wbf[i] = f2bf(src[i & 32767]);
}

// ---------------- proj:
// theta [b][n][128] bf16 row-major.
// phiT  tiled [b][kt=n/32][r=n%32][128d], 16B chunks swizzled c16 ^= (r&7),
//       values pre-scaled by log2(e).
// gTt   tiled [b][kt=n/32][row=d>>1][(d&1)*32+k], 16B chunks c8 ^= (row&7)
//       (128B rows -> conflict-free b128 reads).
__global__ __launch_bounds__(256) void proj_kernel(
    const float* __restrict__ x, const u16* __restrict__ wbf,
    const float* __restrict__ bth, const float* __restrict__ bph,
    const float* __restrict__ bg,
    u16* __restrict__ theta, u16* __restrict__ phiT, u16* __restrict__ gTt)
{
  const int b = blockIdx.y, n0 = blockIdx.x * 64;
  const int tid = threadIdx.x, w = tid >> 6, l = tid & 63;
  const int lr = l & 15, lg = l >> 4;
  __shared__ __align__(16) u16 sx[64 * 256];       // [n][c], swizzled, 32KB

  // stage x-tile: convert f32->bf16 once, transposed to [n][c], coalesced reads
  const float* xb = x + (size_t)b * CIN * NN + n0;
  #pragma unroll
  for (int pass = 0; pass < 8; ++pass) {
    const int cb = w * 8 + pass * 32;
    u16 tmp[8];
    #pragma unroll
    for (int i = 0; i < 8; ++i) tmp[i] = f2bf(xb[(size_t)(cb + i) * NN + l]);
    uint4 v;
    v.x = (unsigned)tmp[0] | ((unsigned)tmp[1] << 16);
    v.y = (unsigned)tmp[2] | ((unsigned)tmp[3] << 16);
    v.z = (unsigned)tmp[4] | ((unsigned)tmp[5] << 16);
    v.w = (unsigned)tmp[6] | ((unsigned)tmp[7] << 16);
    *(uint4*)&sx[l * 256 + (((w + pass * 4) ^ (l & 7)) << 3)] = v;
  }
  __syncthreads();

  #pragma unroll
  for (int dti = 0; dti < 6; ++dti) {
    const int dt = w * 6 + dti;                    // 24 d-tiles over 3 mats
    const int mat = dt >> 3, d0 = (dt & 7) * 16;
    const float* Bv = (mat == 0) ? bth : (mat == 1) ? bph : bg;
    const u16* wrow = wbf + mat * 32768 + (size_t)(d0 + lr) * 256 + lg * 8;
    bf8 wf[8];
    #pragma unroll
    for (int ks = 0; ks < 8; ++ks) wf[ks] = *(const bf8*)(wrow + ks * 32);

    #pragma unroll
    for (int mt = 0; mt < 4; ++mt) {
      f4 acc = {0.f, 0.f, 0.f, 0.f};
      const int row = mt * 16 + lr;
      #pragma unroll
      for (int ks = 0; ks < 8; ++ks) {
        bf8 bx = *(const bf8*)&sx[row * 256 + (((ks * 4 + lg) ^ (lr & 7)) << 3)];
        acc = __builtin_amdgcn_mfma_f32_16x16x32_bf16(wf[ks], bx, acc, 0, 0, 0);
      }
      const int m = n0 + mt * 16 + lr;             // n index
      const int dlo = d0 + lg * 4;
      if (mat == 0) {
        ushort4 h4;
        h4.x = f2bf(acc[0] + Bv[dlo + 0]);
        h4.y = f2bf(acc[1] + Bv[dlo + 1]);
        h4.z = f2bf(acc[2] + Bv[dlo + 2]);
        h4.w = f2bf(acc[3] + Bv[dlo + 3]);
        *(ushort4*)&theta[((size_t)b * NN + m) * CINT + dlo] = h4;
      } else if (mat == 1) {
        const int kt = m >> 5, r32 = m & 31;
        ushort4 h4;
        h4.x = f2bf((acc[0] + Bv[dlo + 0]) * L2E);
        h4.y = f2bf((acc[1] + Bv[dlo + 1]) * L2E);
        h4.z = f2bf((acc[2] + Bv[dlo + 2]) * L2E);
        h4.w = f2bf((acc[3] + Bv[dlo + 3]) * L2E);
        *(ushort4*)&phiT[((size_t)(b * 128 + kt)) * 4096 + r32 * 128 +
                         ((((dlo >> 3) ^ (r32 & 7))) << 3) + (dlo & 7)] = h4;
      } else {
        const int kt = m >> 5, kk = m & 31;
        #pragma unroll
        for (int r = 0; r < 4; ++r) {
          const int d = dlo + r;
          const int grow = d >> 1;
          const int chunk = (((d & 1) * 4 + (kk >> 3)) ^ (grow & 7));
          gTt[((size_t)(b * 128 + kt)) * 4096 + grow * 64 + chunk * 8 + (kk & 7)]
              = f2bf(acc[r] + Bv[d]);
        }
      }
    }
  }
}

// ---------------- attn: 8 waves = 4 q-waves (32 q) x 2 k-halves; KT=32.
// 2-buffer glds16 pipeline; P never touches LDS (cvt_pk + permlane swaps).
__global__ __launch_bounds__(512, 2) void attn_kernel(
    const u16* __restrict__ theta, const u16* __restrict__ phiT,
    const u16* __restrict__ gTt, float* __restrict__ out)
{
  const int b  = blockIdx.y;
  const int t_ = threadIdx.x;
  const int w  = t_ >> 6;
  const int l  = t_ & 63;
  const int lr = l & 15, lg = l >> 4;
  const int h  = w >> 2, wq = w & 3;
  const int qw = blockIdx.x * 128 + wq * 32;

  // LDS: phi 2h x 2buf x 8KB (0..32K) | g same (32K..64K) | rs 2KB
  __shared__ __align__(16) char smem[67584];
  u16* sphi_b = (u16*)smem;
  u16* sg_b   = (u16*)(smem + 32768);

  const u16* th = theta + (size_t)b * NN * CINT;
  bf8 qf[2][4];
  #pragma unroll
  for (int qt = 0; qt < 2; ++qt)
    #pragma unroll
    for (int ds = 0; ds < 4; ++ds)
      qf[qt][ds] = *(const bf8*)(th + (size_t)(qw + qt * 16 + lr) * CINT + ds * 32 + lg * 8);

  f4 y[2][8];
  #pragma unroll
  for (int qt = 0; qt < 2; ++qt)
    #pragma unroll
    for (int dt = 0; dt < 8; ++dt) y[qt][dt] = (f4){0.f, 0.f, 0.f, 0.f};
  float rs[2] = {0.f, 0.f};

  const char* psrc = (const char*)(phiT + (size_t)(b * 128 + h * 64) * 4096) +
                     wq * 2048 + l * 16;
  const char* gsrc = (const char*)(gTt + (size_t)(b * 128 + h * 64) * 4096) +
                     wq * 2048 + l * 16;

  #define STAGE(BUF, T)                                                    \
    {                                                                      \
      const char* sp = psrc + (size_t)(T) * 8192;                          \
      const char* sq = gsrc + (size_t)(T) * 8192;                          \
      char* lp = (char*)(sphi_b + (h * 2 + (BUF)) * 4096) + wq * 2048;     \
      char* lq = (char*)(sg_b + (h * 2 + (BUF)) * 4096) + wq * 2048;       \
      glds16(sp, lp); glds16(sp + 1024, lp + 1024);                        \
      glds16(sq, lq); glds16(sq + 1024, lq + 1024);                        \
    }

  STAGE(0, 0);
  asm volatile("s_waitcnt vmcnt(0)" ::: "memory");
  __builtin_amdgcn_s_barrier();
  __builtin_amdgcn_sched_barrier(0);

  int cur = 0;
  for (int t = 0; t < 64; ++t) {
    if (t < 63) STAGE(cur ^ 1, t + 1);

    const u16* PH = sphi_b + (h * 2 + cur) * 4096;
    const u16* GG = sg_b + (h * 2 + cur) * 4096;

    // ---- swapped QK^T: A = phi (k rows), B = theta (q rows)
    f4 s[2][2];
    s[0][0] = (f4){0.f,0.f,0.f,0.f}; s[0][1] = (f4){0.f,0.f,0.f,0.f};
    s[1][0] = (f4){0.f,0.f,0.f,0.f}; s[1][1] = (f4){0.f,0.f,0.f,0.f};
    __builtin_amdgcn_s_setprio(1);
    #pragma unroll
    for (int st = 0; st < 2; ++st) {
      const u16* base = PH + (st * 16 + lr) * 128;
      #pragma unroll
      for (int ds = 0; ds < 4; ++ds) {
        bf8 af = *(const bf8*)(base + (((ds * 4 + lg) ^ (lr & 7)) << 3));
        s[0][st] = __builtin_amdgcn_mfma_f32_16x16x32_bf16(af, qf[0][ds], s[0][st], 0, 0, 0);
        s[1][st] = __builtin_amdgcn_mfma_f32_16x16x32_bf16(af, qf[1][ds], s[1][st], 0, 0, 0);
      }
    }
    __builtin_amdgcn_s_setprio(0);

    // ---- g B-fragments: row = d>>1 packed, conflict-free
    bf8 gfr[8];
    #pragma unroll
    for (int dt = 0; dt < 8; ++dt) {
      const int grow = dt * 8 + (lr >> 1);
      const int chunk = (((lr & 1) * 4 + lg) ^ (grow & 7));
      gfr[dt] = *(const bf8*)(GG + grow * 64 + chunk * 8);
    }

    // ---- per qt: exp2 -> in-register P (cvt_pk + permlane), PV
    #pragma unroll
    for (int qt = 0; qt < 2; ++qt) {
      float p0 = __builtin_amdgcn_exp2f(s[qt][0][0]);
      float p1 = __builtin_amdgcn_exp2f(s[qt][0][1]);
      float p2 = __builtin_amdgcn_exp2f(s[qt][0][2]);
      float p3 = __builtin_amdgcn_exp2f(s[qt][0][3]);
      float p4 = __builtin_amdgcn_exp2f(s[qt][1][0]);
      float p5 = __builtin_amdgcn_exp2f(s[qt][1][1]);
      float p6 = __builtin_amdgcn_exp2f(s[qt][1][2]);
      float p7 = __builtin_amdgcn_exp2f(s[qt][1][3]);
      rs[qt] += ((p0 + p1) + (p2 + p3)) + ((p4 + p5) + (p6 + p7));

      // w0,w1 = st0 pairs; w2,w3 = st1 pairs (k = st*16 + lg*4 + r)
      int w0 = cvtpk(p0, p1), w1 = cvtpk(p2, p3);
      int w2 = cvtpk(p4, p5), w3 = cvtpk(p6, p7);
      // (pa0,pa2) from (w0,w2); (pa1,pa3) from (w1,w3)
      asm volatile("v_permlane32_swap_b32 %0, %1" : "+v"(w0), "+v"(w2));
      asm volatile("v_permlane16_swap_b32 %0, %1" : "+v"(w0), "+v"(w2));
      asm volatile("v_permlane32_swap_b32 %0, %1" : "+v"(w1), "+v"(w3));
      asm volatile("v_permlane16_swap_b32 %0, %1" : "+v"(w1), "+v"(w3));
      int pai[4] = {w0, w1, w2, w3};   // k = lg*8 + {0,1},{2,3},{4,5},{6,7}
      bf8 paf = __builtin_bit_cast(bf8, *(int4*)pai);

      __builtin_amdgcn_s_setprio(1);
      #pragma unroll
      for (int dt = 0; dt < 8; ++dt)
        y[qt][dt] = __builtin_amdgcn_mfma_f32_16x16x32_bf16(paf, gfr[dt], y[qt][dt], 0, 0, 0);
      __builtin_amdgcn_s_setprio(0);
    }

    if (t < 63) asm volatile("s_waitcnt vmcnt(0)" ::: "memory");
    __builtin_amdgcn_s_barrier();
    __builtin_amdgcn_sched_barrier(0);
    cur ^= 1;
  }

  // ---- combine the two k-halves through LDS (tiles dead)
  #pragma unroll
  for (int qt = 0; qt < 2; ++qt) {
    rs[qt] += __shfl_xor(rs[qt], 16);
    rs[qt] += __shfl_xor(rs[qt], 32);
  }
  __syncthreads();
  float* ycomb  = (float*)smem;            // 64KB
  float* rscomb = (float*)(smem + 65536);  // 2KB
  if (h == 1) {
    #pragma unroll
    for (int qt = 0; qt < 2; ++qt) {
      #pragma unroll
      for (int dt = 0; dt < 8; ++dt)
        *(f4*)&ycomb[wq * 4096 + (qt * 8 + dt) * 256 + l * 4] = y[qt][dt];
      rscomb[wq * 128 + qt * 64 + l] = rs[qt];
    }
  }
  __syncthreads();
  if (h == 0) {
    #pragma unroll
    for (int qt = 0; qt < 2; ++qt) {
      #pragma unroll
      for (int dt = 0; dt < 8; ++dt)
        y[qt][dt] += *(const f4*)&ycomb[wq * 4096 + (qt * 8 + dt) * 256 + l * 4];
      rs[qt] += rscomb[wq * 128 + qt * 64 + l];
    }
    float* ob = out + (size_t)b * CINT * NN;
    #pragma unroll
    for (int qt = 0; qt < 2; ++qt) {
      f4 rsi;
      #pragma unroll
      for (int r = 0; r < 4; ++r)
        rsi[r] = 1.0f / __shfl(rs[qt], lg * 4 + r, 64);
      #pragma unroll
      for (int dt = 0; dt < 8; ++dt) {
        f4 v = y[qt][dt] * rsi;
        *(float4*)&ob[(size_t)(dt * 16 + lr) * NN + qw + qt * 16 + lg * 4] = *(float4*)&v;
      }
    }
  }
}

extern "C" void kernel_launch(void* const* d_in, const int* in_sizes, int n_in,
                              void* d_out, int out_size, void* d_ws, size_t ws_size,
                              hipStream_t stream) {
  const float* x   = (const float*)d_in[0];
  const float* wth = (const float*)d_in[1];
  const float* bth = (const float*)d_in[2];
  const float* wph = (const float*)d_in[3];
  const float* bph = (const float*)d_in[4];
  const float* wg  = (const float*)d_in[5];
  const float* bg  = (const float*)d_in[6];
  float* out = (float*)d_out;

  u16* theta = (u16*)d_ws;
  u16* phiT  = theta + (size_t)B_ * NN * CINT;
  u16* gTt   = phiT  + (size_t)B_ * NN * CINT;
  u16* wbf   = gTt   + (size_t)B_ * NN * CINT;

  hipLaunchKernelGGL(prep_kernel, dim3(384), dim3(256), 0, stream, wth, wph, wg, wbf);
  hipLaunchKernelGGL(proj_kernel, dim3(64, 8), dim3(256), 0, stream,
                     x, wbf, bth, bph, bg, theta, phiT, gTt);
  hipLaunchKernelGGL(attn_kernel, dim3(32, 8), dim3(512), 0, stream,
                     theta, phiT, gTt, out);
}